// Round 9
// baseline (300.208 us; speedup 1.0000x reference)
//
#include <hip/hip_runtime.h>
#include <hip/hip_bf16.h>

#define NNODES 50000
#define NEDGES 800000
#define NFEAT 128
#define NHID 128
#define NCLASS 10
#define NGRAPHS 256

#define NB 391   // (NNODES+127)/128 buckets of 128 nodes
#define HB 128   // histogram/scatter blocks

typedef __attribute__((ext_vector_type(8))) short short8;
typedef __attribute__((ext_vector_type(4))) short short4v;
typedef __attribute__((ext_vector_type(4))) float floatx4;

__device__ __forceinline__ float bf2f(unsigned short u) {
    union { unsigned i; float f; } c; c.i = ((unsigned)u) << 16; return c.f;
}
__device__ __forceinline__ unsigned short f2bf(float f) {
    union { float f; unsigned i; } c; c.f = f;
    unsigned x = c.i;
    unsigned r = (x + 0x7fffu + ((x >> 16) & 1u)) >> 16;
    return (unsigned short)r;
}
__device__ __forceinline__ float blo(unsigned v) { return bf2f((unsigned short)(v & 0xffffu)); }
__device__ __forceinline__ float bhi(unsigned v) { return bf2f((unsigned short)(v >> 16)); }

__device__ __forceinline__ void gload_lds16(const void* gsrc, void* ldst) {
    __builtin_amdgcn_global_load_lds(
        (const __attribute__((address_space(1))) void*)gsrc,
        (__attribute__((address_space(3))) void*)ldst, 16, 0, 0);
}

// ---------------- atomic-free CSR build: two-level counting sort ----------------
__global__ __launch_bounds__(256) void k_hist(const int* __restrict__ dst,
                                              int* __restrict__ hist) {
    __shared__ int lh[NB];
    int tid = threadIdx.x;
    for (int b = tid; b < NB; b += 256) lh[b] = 0;
    __syncthreads();
    for (int i = blockIdx.x * 256 + tid; i < NEDGES; i += HB * 256)
        atomicAdd(&lh[dst[i] >> 7], 1);
    __syncthreads();
    for (int b = tid; b < NB; b += 256) hist[b * HB + blockIdx.x] = lh[b];
}

__global__ __launch_bounds__(512) void k_scan2(const int* __restrict__ hist,
                                               int* __restrict__ base,
                                               int* __restrict__ boff,
                                               int* __restrict__ row_ptr,
                                               const int* __restrict__ batch,
                                               int* __restrict__ gstart) {
    __shared__ int tot[NB];
    int tid = threadIdx.x;
    int wid = tid >> 6, l = tid & 63;
    if (tid <= NGRAPHS) {
        int lo = 0, hi = NNODES;
        while (lo < hi) { int mid = (lo + hi) >> 1; if (batch[mid] < tid) lo = mid + 1; else hi = mid; }
        gstart[tid] = lo;
    }
    for (int q = wid; q < NB; q += 8) {
        int h0 = hist[q * HB + l];
        int h1 = hist[q * HB + 64 + l];
        int s0 = h0, s1 = h1;
        #pragma unroll
        for (int d = 1; d < 64; d <<= 1) {
            int y0 = __shfl_up(s0, d);
            int y1 = __shfl_up(s1, d);
            if (l >= d) { s0 += y0; s1 += y1; }
        }
        int t0 = __shfl(s0, 63);
        base[q * HB + l] = s0 - h0;
        base[q * HB + 64 + l] = s1 - h1 + t0;
        if (l == 63) tot[q] = t0 + s1;
    }
    __syncthreads();
    if (wid == 0) {
        int carry = 0;
        #pragma unroll
        for (int c = 0; c < (NB + 63) / 64; ++c) {
            int i = c * 64 + l;
            int v = (i < NB) ? tot[i] : 0;
            int s = v;
            #pragma unroll
            for (int d = 1; d < 64; d <<= 1) { int y = __shfl_up(s, d); if (l >= d) s += y; }
            if (i < NB) boff[i] = carry + s - v;
            carry += __shfl(s, 63);
        }
        if (l == 0) { boff[NB] = carry; row_ptr[NNODES] = carry; }
    }
}

__global__ __launch_bounds__(256) void k_scatter(const int* __restrict__ src,
                                                 const int* __restrict__ dst,
                                                 const int* __restrict__ base,
                                                 const int* __restrict__ boff,
                                                 unsigned* __restrict__ ebuf) {
    __shared__ int cur[NB];
    int tid = threadIdx.x;
    for (int b = tid; b < NB; b += 256) cur[b] = boff[b] + base[b * HB + blockIdx.x];
    __syncthreads();
    for (int i = blockIdx.x * 256 + tid; i < NEDGES; i += HB * 256) {
        int d = dst[i];
        int bin = d >> 7;
        int pos = atomicAdd(&cur[bin], 1);                    // LDS atomic
        ebuf[pos] = (unsigned)src[i] | ((unsigned)(d & 127) << 16);
    }
}

__global__ __launch_bounds__(256) void k_bcsr(const unsigned* __restrict__ ebuf,
                                              const int* __restrict__ boff,
                                              int* __restrict__ row_ptr,
                                              int* __restrict__ esrc) {
    __shared__ int deg[128];
    __shared__ int curs[128];
    int tid = threadIdx.x;
    int b = blockIdx.x;
    int s = boff[b], e = boff[b + 1];
    if (tid < 128) deg[tid] = 0;
    __syncthreads();
    for (int i = s + tid; i < e; i += 256) atomicAdd(&deg[ebuf[i] >> 16], 1);
    __syncthreads();
    if (tid == 0) {
        int run = s;
        for (int i = 0; i < 128; ++i) { curs[i] = run; run += deg[i]; }
    }
    __syncthreads();
    if (tid < 128) {
        int node = b * 128 + tid;
        if (node < NNODES) row_ptr[node] = curs[tid];
    }
    __syncthreads();
    for (int i = s + tid; i < e; i += 256) {
        unsigned pk = ebuf[i];
        int pos = atomicAdd(&curs[pk >> 16], 1);              // LDS atomic
        esrc[pos] = (int)(pk & 0xffffu);
    }
}

// ---------------- bf16 conversion (vectorized x4) of x and all 6 W matrices ------
__global__ void k_cvt(const float* __restrict__ x,
                      const float* __restrict__ w0, const float* __restrict__ w1,
                      const float* __restrict__ w2, const float* __restrict__ w3,
                      const float* __restrict__ w4, const float* __restrict__ w5,
                      unsigned short* __restrict__ xb, unsigned short* __restrict__ wb) {
    int gid = blockIdx.x * blockDim.x + threadIdx.x;   // group of 4 elements
    const int NX4 = NNODES * NFEAT / 4;
    const floatx4* srcv;
    short4v* dstv;
    if (gid < NX4) {
        srcv = (const floatx4*)x + gid;
        dstv = (short4v*)xb + gid;
    } else {
        int j = gid - NX4;
        if (j >= 6 * 4096) return;
        int m = j >> 12;
        int o4 = j & 4095;
        const float* w = (m == 0) ? w0 : (m == 1) ? w1 : (m == 2) ? w2
                       : (m == 3) ? w3 : (m == 4) ? w4 : w5;
        srcv = (const floatx4*)w + o4;
        dstv = (short4v*)wb + (m * 4096 + o4);
    }
    floatx4 v = *srcv;
    short4v o;
    #pragma unroll
    for (int k = 0; k < 4; ++k) o[k] = (short)f2bf(v[k]);
    *dstv = o;
}

// ---------------- fused layer v3: 32 rows/block, 256 threads, pipelined gather -----
// Grid 1563 blocks (6.1/CU supply, 8/CU wave-slot cap). Per block: stage 32 feat rows
// (A2) via global_load_lds; 4 waves gather-aggregate 8 nodes each into LDS A1
// (row_ptr preloaded per-wave via lane+shfl; next node's esrc chunk prefetched during
// current node's gathers). One barrier. MFMA: wave w owns col stripes {2w, 2w+1}.
__global__ __launch_bounds__(256, 8) void k_layer(const unsigned short* __restrict__ feat,
                                                  const int* __restrict__ row_ptr,
                                                  const int* __restrict__ esrc,
                                                  const unsigned short* __restrict__ Bn,
                                                  const unsigned short* __restrict__ Bs,
                                                  const float* __restrict__ bias,
                                                  unsigned short* __restrict__ out) {
    __shared__ __align__(16) unsigned short ldsA[2][4096];   // [0]=agg, [1]=feat: 32 rows x 128
    int w = threadIdx.x >> 6;     // 0..3
    int l = threadIdx.x & 63;
    int r = l & 15;
    int gk = l >> 4;
    int m0 = blockIdx.x * 32;

    // ---- stage A2 = feat rows, pre-swizzled source columns ----
    {
        int c = l & 15;
        #pragma unroll
        for (int is = 0; is < 2; ++is) {
            int row = is * 16 + (w << 2) + (l >> 4);
            int nrow = m0 + row; if (nrow >= NNODES) nrow = NNODES - 1;
            gload_lds16(feat + (size_t)nrow * 128 + ((c ^ (row & 15)) << 3),
                        &ldsA[1][(is * 16 + (w << 2)) * 128]);
        }
    }

    // ---- gather-mean 8 nodes per wave into A1, idx prefetch pipeline ----
    const unsigned* feat32 = (const unsigned*)feat;  // 2 bf16/dword, row stride 64
    unsigned* A1 = (unsigned*)&ldsA[0][0];           // dword view, row stride 64
    int n0 = m0 + (w << 3);
    int rpl = row_ptr[min(n0 + l, NNODES)];          // lanes 0..8 carry the 9 row_ptrs
    int beg = __shfl(rpl, 0);
    int nb  = __shfl(rpl, 1) - beg;
    int myidx = (l < (nb < 64 ? nb : 64)) ? esrc[beg + l] : 0;

    #pragma unroll 1
    for (int i = 0; i < 8; ++i) {
        int nbeg = 0, nnb = 0, nmy = 0;
        if (i < 7) {                                  // prefetch next node's first chunk
            nbeg = __shfl(rpl, i + 1);
            nnb  = __shfl(rpl, i + 2) - nbeg;
            nmy = (l < (nnb < 64 ? nnb : 64)) ? esrc[nbeg + l] : 0;
        }
        float a0 = 0.f, a1 = 0.f;
        for (int base = 0; base < nb; base += 64) {
            int rem = nb - base;
            int cnt = rem < 64 ? rem : 64;
            int idxv = (base == 0) ? myidx
                     : ((l < cnt) ? esrc[beg + base + l] : 0);
            int j = 0;
            for (; j + 8 <= cnt; j += 8) {
                int s0 = __shfl(idxv, j);
                int s1 = __shfl(idxv, j + 1);
                int s2 = __shfl(idxv, j + 2);
                int s3 = __shfl(idxv, j + 3);
                int s4 = __shfl(idxv, j + 4);
                int s5 = __shfl(idxv, j + 5);
                int s6 = __shfl(idxv, j + 6);
                int s7 = __shfl(idxv, j + 7);
                unsigned v0 = feat32[s0 * 64 + l];
                unsigned v1 = feat32[s1 * 64 + l];
                unsigned v2 = feat32[s2 * 64 + l];
                unsigned v3 = feat32[s3 * 64 + l];
                unsigned v4 = feat32[s4 * 64 + l];
                unsigned v5 = feat32[s5 * 64 + l];
                unsigned v6 = feat32[s6 * 64 + l];
                unsigned v7 = feat32[s7 * 64 + l];
                a0 += ((blo(v0) + blo(v1)) + (blo(v2) + blo(v3)))
                    + ((blo(v4) + blo(v5)) + (blo(v6) + blo(v7)));
                a1 += ((bhi(v0) + bhi(v1)) + (bhi(v2) + bhi(v3)))
                    + ((bhi(v4) + bhi(v5)) + (bhi(v6) + bhi(v7)));
            }
            for (; j + 4 <= cnt; j += 4) {
                int s0 = __shfl(idxv, j);
                int s1 = __shfl(idxv, j + 1);
                int s2 = __shfl(idxv, j + 2);
                int s3 = __shfl(idxv, j + 3);
                unsigned v0 = feat32[s0 * 64 + l];
                unsigned v1 = feat32[s1 * 64 + l];
                unsigned v2 = feat32[s2 * 64 + l];
                unsigned v3 = feat32[s3 * 64 + l];
                a0 += (blo(v0) + blo(v1)) + (blo(v2) + blo(v3));
                a1 += (bhi(v0) + bhi(v1)) + (bhi(v2) + bhi(v3));
            }
            for (; j < cnt; ++j) {
                int s0 = __shfl(idxv, j);
                unsigned v0 = feat32[s0 * 64 + l];
                a0 += blo(v0);
                a1 += bhi(v0);
            }
        }
        int row = (w << 3) + i;
        float inv = 1.0f / (float)max(nb, 1);
        unsigned o = ((unsigned)f2bf(a0 * inv)) | (((unsigned)f2bf(a1 * inv)) << 16);
        int c = l >> 2;
        A1[row * 64 + ((c ^ (row & 15)) << 2) + (l & 3)] = o;   // swizzled write
        beg = nbeg; nb = nnb; myidx = nmy;
    }

    // ---- B fragments: wave w owns col stripes {2w, 2w+1} ----
    short8 bf[2][8];
    float bias_v[2];
    #pragma unroll
    for (int s = 0; s < 2; ++s) {
        int stripe = (w << 1) + s;
        #pragma unroll
        for (int kt = 0; kt < 8; ++kt) {
            const unsigned short* Bbase = (kt < 4 ? Bn : Bs);
            bf[s][kt] = *(const short8*)(Bbase + (stripe * 16 + r) * 128 + (kt & 3) * 32 + gk * 8);
        }
        bias_v[s] = bias[stripe * 16 + r];
    }

    __syncthreads();   // drains vmcnt (gload_lds) + lgkm (ds_write) for all waves

    // ---- MFMA phase: 2 row-tiles of 16; af loaded once per tile, used by 2 stripes --
    #pragma unroll
    for (int t = 0; t < 2; ++t) {
        short8 af[8];
        #pragma unroll
        for (int kt = 0; kt < 8; ++kt) {
            int half = kt >> 2;                          // 0: agg@Wn, 1: feat@Ws
            int Cr = ((((kt & 3) << 2) + gk) ^ r) << 3;
            af[kt] = *(const short8*)(&ldsA[half][(t * 16 + r) * 128 + Cr]);
        }
        #pragma unroll
        for (int s = 0; s < 2; ++s) {
            floatx4 acc = {0.f, 0.f, 0.f, 0.f};
            #pragma unroll
            for (int kt = 0; kt < 8; ++kt)
                acc = __builtin_amdgcn_mfma_f32_16x16x32_bf16(af[kt], bf[s][kt], acc, 0, 0, 0);
            int o = ((w << 1) + s) * 16 + r;
            #pragma unroll
            for (int j = 0; j < 4; ++j) {
                int mrow = m0 + t * 16 + gk * 4 + j;
                if (mrow < NNODES) {
                    float v = acc[j] + bias_v[s];
                    v = v > 0.f ? v : 0.f;
                    out[mrow * 128 + o] = f2bf(v);
                }
            }
        }
    }
}

// ---------------- mean pool: 8 partial-sum blocks per graph ----------------
__global__ __launch_bounds__(256) void k_pool(const unsigned short* __restrict__ h,
                                              const int* __restrict__ gstart,
                                              float* __restrict__ part) {
    int g = blockIdx.x >> 3;
    int c = blockIdx.x & 7;
    int s = gstart[g], e = gstart[g + 1];
    int len = e - s;
    int cs = s + (len * c) / 8;
    int ce = s + (len * (c + 1)) / 8;
    int w = threadIdx.x >> 6;
    int l = threadIdx.x & 63;
    const unsigned* h32 = (const unsigned*)h;
    float a0 = 0.f, a1 = 0.f;
    for (int n = cs + w; n < ce; n += 4) {
        unsigned v = h32[n * 64 + l];
        a0 += blo(v);
        a1 += bhi(v);
    }
    __shared__ float red[4][128];
    red[w][2 * l] = a0;
    red[w][2 * l + 1] = a1;
    __syncthreads();
    if (w == 0) {
        float r0 = (red[0][2 * l] + red[1][2 * l]) + (red[2][2 * l] + red[3][2 * l]);
        float r1 = (red[0][2 * l + 1] + red[1][2 * l + 1]) + (red[2][2 * l + 1] + red[3][2 * l + 1]);
        float* dst = part + (size_t)(g * 8 + c) * 128;
        dst[2 * l] = r0;
        dst[2 * l + 1] = r1;
    }
}

// ---------------- head: reduce partials, logits + log_softmax (f32) ----------------
__global__ __launch_bounds__(128) void k_head(const float* __restrict__ part,
                                              const int* __restrict__ gstart,
                                              const float* __restrict__ Wlin,
                                              const float* __restrict__ blin,
                                              float* __restrict__ out) {
    int gi = blockIdx.x;
    __shared__ float gl[128];
    __shared__ float lg[NCLASS];
    int t = threadIdx.x;
    float s = 0.f;
    #pragma unroll
    for (int c = 0; c < 8; ++c) s += part[(size_t)(gi * 8 + c) * 128 + t];
    int len = gstart[gi + 1] - gstart[gi];
    gl[t] = s / (float)max(len, 1);
    __syncthreads();
    if (t < NCLASS) {
        float a = blin[t];
        #pragma unroll 16
        for (int i = 0; i < 128; ++i) a += gl[i] * Wlin[t * 128 + i];
        lg[t] = a;
    }
    __syncthreads();
    if (t == 0) {
        float m = lg[0];
        for (int k = 1; k < NCLASS; ++k) m = fmaxf(m, lg[k]);
        float sum = 0.f;
        for (int k = 0; k < NCLASS; ++k) sum += expf(lg[k] - m);
        float ls = logf(sum) + m;
        for (int k = 0; k < NCLASS; ++k) out[gi * NCLASS + k] = lg[k] - ls;
    }
}

extern "C" void kernel_launch(void* const* d_in, const int* in_sizes, int n_in,
                              void* d_out, int out_size, void* d_ws, size_t ws_size,
                              hipStream_t stream) {
    const float* x    = (const float*)d_in[0];
    const int*   ei   = (const int*)d_in[1];
    const int*   src  = ei;
    const int*   dst  = ei + NEDGES;
    const int*   batch= (const int*)d_in[2];
    const float* W1n  = (const float*)d_in[3];
    const float* b1   = (const float*)d_in[4];
    const float* W1s  = (const float*)d_in[5];
    const float* W2n  = (const float*)d_in[6];
    const float* b2   = (const float*)d_in[7];
    const float* W2s  = (const float*)d_in[8];
    const float* W3n  = (const float*)d_in[9];
    const float* b3   = (const float*)d_in[10];
    const float* W3s  = (const float*)d_in[11];
    const float* Wlin = (const float*)d_in[12];
    const float* blin = (const float*)d_in[13];
    float* out = (float*)d_out;

    char* p = (char*)d_ws;
    auto alloc = [&](size_t bytes) -> void* {
        void* r = (void*)p;
        p += (bytes + 255) & ~(size_t)255;
        return r;
    };
    unsigned short* xb   = (unsigned short*)alloc((size_t)NNODES * NFEAT * 2);
    unsigned short* hA   = (unsigned short*)alloc((size_t)NNODES * NHID * 2);
    unsigned short* hB   = (unsigned short*)alloc((size_t)NNODES * NHID * 2);
    unsigned short* wb   = (unsigned short*)alloc((size_t)6 * 16384 * 2);
    int* hist    = (int*)alloc((size_t)NB * HB * 4);
    int* base    = (int*)alloc((size_t)NB * HB * 4);
    int* boff    = (int*)alloc((size_t)(NB + 1) * 4);
    int* row_ptr = (int*)alloc((size_t)(NNODES + 1) * 4);
    int* gstart  = (int*)alloc((size_t)(NGRAPHS + 1) * 4);
    unsigned* ebuf = (unsigned*)alloc((size_t)NEDGES * 4);
    int* esrc    = (int*)alloc((size_t)NEDGES * 4);
    float* part  = (float*)alloc((size_t)NGRAPHS * 8 * NHID * 4);

    // CSR build (atomic-free counting sort) + graph ranges
    k_hist<<<HB, 256, 0, stream>>>(dst, hist);
    k_scan2<<<1, 512, 0, stream>>>(hist, base, boff, row_ptr, batch, gstart);
    k_scatter<<<HB, 256, 0, stream>>>(src, dst, base, boff, ebuf);
    k_bcsr<<<NB, 256, 0, stream>>>(ebuf, boff, row_ptr, esrc);

    // convert x + weights to bf16 (4 elems/thread)
    {
        int total4 = NNODES * NFEAT / 4 + 6 * 4096;
        k_cvt<<<(total4 + 255) / 256, 256, 0, stream>>>(x, W1n, W1s, W2n, W2s, W3n, W3s, xb, wb);
    }

    const int layerGrid = (NNODES + 31) / 32;

    // fused layers: gather-mean + [agg|feat] @ [Wn|Ws]^T + bias + relu
    k_layer<<<layerGrid, 256, 0, stream>>>(xb, row_ptr, esrc, wb + 0 * 16384, wb + 1 * 16384, b1, hA);
    k_layer<<<layerGrid, 256, 0, stream>>>(hA, row_ptr, esrc, wb + 2 * 16384, wb + 3 * 16384, b2, hB);
    k_layer<<<layerGrid, 256, 0, stream>>>(hB, row_ptr, esrc, wb + 4 * 16384, wb + 5 * 16384, b3, hA);

    // pool + head
    k_pool<<<NGRAPHS * 8, 256, 0, stream>>>(hA, gstart, part);
    k_head<<<NGRAPHS, 128, 0, stream>>>(part, gstart, Wlin, blin, out);
}

// Round 10
// 228.828 us; speedup vs baseline: 1.3119x; 1.3119x over previous
//
#include <hip/hip_runtime.h>
#include <hip/hip_bf16.h>

#define NNODES 50000
#define NEDGES 800000
#define NFEAT 128
#define NHID 128
#define NCLASS 10
#define NGRAPHS 256

#define NB 391   // (NNODES+127)/128 buckets of 128 nodes
#define HB 512   // histogram/scatter blocks

typedef __attribute__((ext_vector_type(8))) short short8;
typedef __attribute__((ext_vector_type(4))) short short4v;
typedef __attribute__((ext_vector_type(4))) float floatx4;

__device__ __forceinline__ float bf2f(unsigned short u) {
    union { unsigned i; float f; } c; c.i = ((unsigned)u) << 16; return c.f;
}
__device__ __forceinline__ unsigned short f2bf(float f) {
    union { float f; unsigned i; } c; c.f = f;
    unsigned x = c.i;
    unsigned r = (x + 0x7fffu + ((x >> 16) & 1u)) >> 16;
    return (unsigned short)r;
}
__device__ __forceinline__ float blo(unsigned v) { return bf2f((unsigned short)(v & 0xffffu)); }
__device__ __forceinline__ float bhi(unsigned v) { return bf2f((unsigned short)(v >> 16)); }

__device__ __forceinline__ void gload_lds16(const void* gsrc, void* ldst) {
    __builtin_amdgcn_global_load_lds(
        (const __attribute__((address_space(1))) void*)gsrc,
        (__attribute__((address_space(3))) void*)ldst, 16, 0, 0);
}

// ---------------- atomic-free CSR build: two-level counting sort ----------------
// hist layout TRANSPOSED: hist[bucket * HB + histblock] so bucket rows are contiguous.
__global__ __launch_bounds__(256) void k_hist(const int* __restrict__ dst,
                                              int* __restrict__ hist) {
    __shared__ int lh[NB];
    int tid = threadIdx.x;
    for (int b = tid; b < NB; b += 256) lh[b] = 0;
    __syncthreads();
    for (int i = blockIdx.x * 256 + tid; i < NEDGES; i += HB * 256)
        atomicAdd(&lh[dst[i] >> 7], 1);
    __syncthreads();
    for (int b = tid; b < NB; b += 256) hist[b * HB + blockIdx.x] = lh[b];
}

// Pass 2 (parallel): per-bucket wave scans over HB per-block counts -> base,
// bucket totals -> boff. Also graph starts via binary search on sorted batch.
__global__ __launch_bounds__(512) void k_scan2(const int* __restrict__ hist,
                                               int* __restrict__ base,
                                               int* __restrict__ boff,
                                               int* __restrict__ row_ptr,
                                               const int* __restrict__ batch,
                                               int* __restrict__ gstart) {
    __shared__ int tot[NB];
    int tid = threadIdx.x;
    int wid = tid >> 6, l = tid & 63;
    if (tid <= NGRAPHS) {
        int lo = 0, hi = NNODES;
        while (lo < hi) { int mid = (lo + hi) >> 1; if (batch[mid] < tid) lo = mid + 1; else hi = mid; }
        gstart[tid] = lo;
    }
    // phase A: per-bucket exclusive scan of HB per-block counts (HB/64 chunks)
    for (int q = wid; q < NB; q += 8) {
        int carry = 0;
        #pragma unroll
        for (int c = 0; c < HB / 64; ++c) {
            int h = hist[q * HB + c * 64 + l];
            int s = h;
            #pragma unroll
            for (int d = 1; d < 64; d <<= 1) { int y = __shfl_up(s, d); if (l >= d) s += y; }
            base[q * HB + c * 64 + l] = carry + s - h;
            carry += __shfl(s, 63);
        }
        if (l == 0) tot[q] = carry;
    }
    __syncthreads();
    // phase B: exclusive scan of the NB bucket totals (single wave, 7 chunks)
    if (wid == 0) {
        int carry = 0;
        #pragma unroll
        for (int c = 0; c < (NB + 63) / 64; ++c) {
            int i = c * 64 + l;
            int v = (i < NB) ? tot[i] : 0;
            int s = v;
            #pragma unroll
            for (int d = 1; d < 64; d <<= 1) { int y = __shfl_up(s, d); if (l >= d) s += y; }
            if (i < NB) boff[i] = carry + s - v;
            carry += __shfl(s, 63);
        }
        if (l == 0) { boff[NB] = carry; row_ptr[NNODES] = carry; }
    }
}

// Pass 3: scatter edges into bucket-sorted ebuf; LDS cursors = boff + local base.
__global__ __launch_bounds__(256) void k_scatter(const int* __restrict__ src,
                                                 const int* __restrict__ dst,
                                                 const int* __restrict__ base,
                                                 const int* __restrict__ boff,
                                                 unsigned* __restrict__ ebuf) {
    __shared__ int cur[NB];
    int tid = threadIdx.x;
    for (int b = tid; b < NB; b += 256) cur[b] = boff[b] + base[b * HB + blockIdx.x];
    __syncthreads();
    for (int i = blockIdx.x * 256 + tid; i < NEDGES; i += HB * 256) {
        int d = dst[i];
        int bin = d >> 7;
        int pos = atomicAdd(&cur[bin], 1);                    // LDS atomic
        ebuf[pos] = (unsigned)src[i] | ((unsigned)(d & 127) << 16);
    }
}

// Pass 4: per-bucket local CSR (128 nodes) fully in LDS. esrc stored as ushort.
__global__ __launch_bounds__(256) void k_bcsr(const unsigned* __restrict__ ebuf,
                                              const int* __restrict__ boff,
                                              int* __restrict__ row_ptr,
                                              unsigned short* __restrict__ esrc) {
    __shared__ int deg[128];
    __shared__ int curs[128];
    int tid = threadIdx.x;
    int b = blockIdx.x;
    int s = boff[b], e = boff[b + 1];
    if (tid < 128) deg[tid] = 0;
    __syncthreads();
    for (int i = s + tid; i < e; i += 256) atomicAdd(&deg[ebuf[i] >> 16], 1);
    __syncthreads();
    if (tid == 0) {
        int run = s;
        for (int i = 0; i < 128; ++i) { curs[i] = run; run += deg[i]; }
    }
    __syncthreads();
    if (tid < 128) {
        int node = b * 128 + tid;
        if (node < NNODES) row_ptr[node] = curs[tid];
    }
    __syncthreads();
    for (int i = s + tid; i < e; i += 256) {
        unsigned pk = ebuf[i];
        int pos = atomicAdd(&curs[pk >> 16], 1);              // LDS atomic
        esrc[pos] = (unsigned short)(pk & 0xffffu);
    }
}

// ---------------- bf16 conversion (vectorized x4) of x and all 6 W matrices ------
__global__ void k_cvt(const float* __restrict__ x,
                      const float* __restrict__ w0, const float* __restrict__ w1,
                      const float* __restrict__ w2, const float* __restrict__ w3,
                      const float* __restrict__ w4, const float* __restrict__ w5,
                      unsigned short* __restrict__ xb, unsigned short* __restrict__ wb) {
    int gid = blockIdx.x * blockDim.x + threadIdx.x;   // group of 4 elements
    const int NX4 = NNODES * NFEAT / 4;
    const floatx4* srcv;
    short4v* dstv;
    if (gid < NX4) {
        srcv = (const floatx4*)x + gid;
        dstv = (short4v*)xb + gid;
    } else {
        int j = gid - NX4;
        if (j >= 6 * 4096) return;
        int m = j >> 12;
        int o4 = j & 4095;
        const float* w = (m == 0) ? w0 : (m == 1) ? w1 : (m == 2) ? w2
                       : (m == 3) ? w3 : (m == 4) ? w4 : w5;
        srcv = (const floatx4*)w + o4;
        dstv = (short4v*)wb + (m * 4096 + o4);
    }
    floatx4 v = *srcv;
    short4v o;
    #pragma unroll
    for (int k = 0; k < 4; ++k) o[k] = (short)f2bf(v[k]);
    *dstv = o;
}

// ---------------- fused layer (R8 structure): 64 rows/block, 512 threads ----------
// Phase 1: stage 64 feat rows (A2) via global_load_lds; 8 waves gather-aggregate
// 8 nodes each into LDS A1 (XOR-swizzled bf16 rows, f32 acc), 8 row-loads in flight.
// Phase 2 (one barrier): wave w owns col stripe w, B frags in regs, A via ds_read.
__global__ __launch_bounds__(512, 6) void k_layer(const unsigned short* __restrict__ feat,
                                                  const int* __restrict__ row_ptr,
                                                  const unsigned short* __restrict__ esrc,
                                                  const unsigned short* __restrict__ Bn,
                                                  const unsigned short* __restrict__ Bs,
                                                  const float* __restrict__ bias,
                                                  unsigned short* __restrict__ out) {
    __shared__ __align__(16) unsigned short ldsA[2][8192];   // [0]=agg, [1]=feat: 64 rows x 128
    int w = threadIdx.x >> 6;
    int l = threadIdx.x & 63;
    int r = l & 15;               // row-in-tile for A, col-in-tile for B/C
    int gk = l >> 4;              // k-group (8 elements each)
    int m0 = blockIdx.x * 64;

    // ---- stage A2 = feat rows (x @ Ws operand), pre-swizzled source columns ----
    {
        int c = l & 15;
        #pragma unroll
        for (int is = 0; is < 2; ++is) {
            int row = is * 32 + (w << 2) + (l >> 4);
            int nrow = m0 + row; if (nrow >= NNODES) nrow = NNODES - 1;
            gload_lds16(feat + (size_t)nrow * 128 + ((c ^ (row & 15)) << 3),
                        &ldsA[1][(is * 32 + (w << 2)) * 128]);
        }
    }

    // ---- gather-mean 8 nodes per wave into A1 (swizzled write), 8-deep MLP ----
    const unsigned* feat32 = (const unsigned*)feat;  // 2 bf16/dword, row stride 64
    unsigned* A1 = (unsigned*)&ldsA[0][0];           // dword view, row stride 64
    #pragma unroll 1
    for (int i = 0; i < 8; ++i) {
        int row = (w << 3) + i;
        int n = m0 + row;
        float a0 = 0.f, a1 = 0.f;
        int nb = 0;
        if (n < NNODES) {
            int beg = row_ptr[n];
            nb = row_ptr[n + 1] - beg;
            for (int base = 0; base < nb; base += 64) {
                int rem = nb - base;
                int cnt = rem < 64 ? rem : 64;
                int myidx = (l < cnt) ? (int)esrc[beg + base + l] : 0;
                int j = 0;
                for (; j + 8 <= cnt; j += 8) {
                    int s0 = __shfl(myidx, j);
                    int s1 = __shfl(myidx, j + 1);
                    int s2 = __shfl(myidx, j + 2);
                    int s3 = __shfl(myidx, j + 3);
                    int s4 = __shfl(myidx, j + 4);
                    int s5 = __shfl(myidx, j + 5);
                    int s6 = __shfl(myidx, j + 6);
                    int s7 = __shfl(myidx, j + 7);
                    unsigned v0 = feat32[s0 * 64 + l];
                    unsigned v1 = feat32[s1 * 64 + l];
                    unsigned v2 = feat32[s2 * 64 + l];
                    unsigned v3 = feat32[s3 * 64 + l];
                    unsigned v4 = feat32[s4 * 64 + l];
                    unsigned v5 = feat32[s5 * 64 + l];
                    unsigned v6 = feat32[s6 * 64 + l];
                    unsigned v7 = feat32[s7 * 64 + l];
                    a0 += ((blo(v0) + blo(v1)) + (blo(v2) + blo(v3)))
                        + ((blo(v4) + blo(v5)) + (blo(v6) + blo(v7)));
                    a1 += ((bhi(v0) + bhi(v1)) + (bhi(v2) + bhi(v3)))
                        + ((bhi(v4) + bhi(v5)) + (bhi(v6) + bhi(v7)));
                }
                for (; j + 4 <= cnt; j += 4) {
                    int s0 = __shfl(myidx, j);
                    int s1 = __shfl(myidx, j + 1);
                    int s2 = __shfl(myidx, j + 2);
                    int s3 = __shfl(myidx, j + 3);
                    unsigned v0 = feat32[s0 * 64 + l];
                    unsigned v1 = feat32[s1 * 64 + l];
                    unsigned v2 = feat32[s2 * 64 + l];
                    unsigned v3 = feat32[s3 * 64 + l];
                    a0 += (blo(v0) + blo(v1)) + (blo(v2) + blo(v3));
                    a1 += (bhi(v0) + bhi(v1)) + (bhi(v2) + bhi(v3));
                }
                for (; j < cnt; ++j) {
                    int s0 = __shfl(myidx, j);
                    unsigned v0 = feat32[s0 * 64 + l];
                    a0 += blo(v0);
                    a1 += bhi(v0);
                }
            }
        }
        float inv = 1.0f / (float)max(nb, 1);
        unsigned o = ((unsigned)f2bf(a0 * inv)) | (((unsigned)f2bf(a1 * inv)) << 16);
        int c = l >> 2;                                  // logical 16B chunk 0..15
        A1[row * 64 + ((c ^ (row & 15)) << 2) + (l & 3)] = o;   // swizzled write
    }

    // ---- B fragments (L2-hot, 8 loads) issued before the barrier wait ----
    short8 bf[8];
    #pragma unroll
    for (int kt = 0; kt < 8; ++kt) {
        const unsigned short* Bbase = (kt < 4 ? Bn : Bs);
        bf[kt] = *(const short8*)(Bbase + (w * 16 + r) * 128 + (kt & 3) * 32 + gk * 8);
    }
    int o = w * 16 + r;
    float bias_v = bias[o];

    __syncthreads();   // drains vmcnt (gload_lds) + lgkm (ds_write) for all waves

    // ---- MFMA phase: 4 row-tiles of 16; K processed in 2 halves (VGPR economy) ----
    #pragma unroll
    for (int t = 0; t < 4; ++t) {
        floatx4 acc = {0.f, 0.f, 0.f, 0.f};
        #pragma unroll
        for (int half = 0; half < 2; ++half) {           // 0: agg@Wn, 1: feat@Ws
            short8 af[4];
            #pragma unroll
            for (int kk = 0; kk < 4; ++kk) {
                int Cr = (((kk << 2) + gk) ^ r) << 3;    // swizzled read col
                af[kk] = *(const short8*)(&ldsA[half][(t * 16 + r) * 128 + Cr]);
            }
            #pragma unroll
            for (int kk = 0; kk < 4; ++kk)
                acc = __builtin_amdgcn_mfma_f32_16x16x32_bf16(af[kk], bf[half * 4 + kk], acc, 0, 0, 0);
        }
        // C/D layout: col = lane&15 (=r), row-in-tile = gk*4 + j
        #pragma unroll
        for (int j = 0; j < 4; ++j) {
            int mrow = m0 + t * 16 + gk * 4 + j;
            if (mrow < NNODES) {
                float v = acc[j] + bias_v;
                v = v > 0.f ? v : 0.f;
                out[mrow * 128 + o] = f2bf(v);
            }
        }
    }
}

// ---------------- mean pool: 8 partial-sum blocks per graph ----------------
__global__ __launch_bounds__(256) void k_pool(const unsigned short* __restrict__ h,
                                              const int* __restrict__ gstart,
                                              float* __restrict__ part) {
    int g = blockIdx.x >> 3;
    int c = blockIdx.x & 7;
    int s = gstart[g], e = gstart[g + 1];
    int len = e - s;
    int cs = s + (len * c) / 8;
    int ce = s + (len * (c + 1)) / 8;
    int w = threadIdx.x >> 6;
    int l = threadIdx.x & 63;
    const unsigned* h32 = (const unsigned*)h;
    float a0 = 0.f, a1 = 0.f;
    for (int n = cs + w; n < ce; n += 4) {
        unsigned v = h32[n * 64 + l];
        a0 += blo(v);
        a1 += bhi(v);
    }
    __shared__ float red[4][128];
    red[w][2 * l] = a0;
    red[w][2 * l + 1] = a1;
    __syncthreads();
    if (w == 0) {
        float r0 = (red[0][2 * l] + red[1][2 * l]) + (red[2][2 * l] + red[3][2 * l]);
        float r1 = (red[0][2 * l + 1] + red[1][2 * l + 1]) + (red[2][2 * l + 1] + red[3][2 * l + 1]);
        float* dst = part + (size_t)(g * 8 + c) * 128;
        dst[2 * l] = r0;
        dst[2 * l + 1] = r1;
    }
}

// ---------------- head: reduce partials, logits + log_softmax (f32) ----------------
__global__ __launch_bounds__(128) void k_head(const float* __restrict__ part,
                                              const int* __restrict__ gstart,
                                              const float* __restrict__ Wlin,
                                              const float* __restrict__ blin,
                                              float* __restrict__ out) {
    int gi = blockIdx.x;
    __shared__ float gl[128];
    __shared__ float lg[NCLASS];
    int t = threadIdx.x;
    float s = 0.f;
    #pragma unroll
    for (int c = 0; c < 8; ++c) s += part[(size_t)(gi * 8 + c) * 128 + t];
    int len = gstart[gi + 1] - gstart[gi];
    gl[t] = s / (float)max(len, 1);
    __syncthreads();
    if (t < NCLASS) {
        float a = blin[t];
        #pragma unroll 16
        for (int i = 0; i < 128; ++i) a += gl[i] * Wlin[t * 128 + i];
        lg[t] = a;
    }
    __syncthreads();
    if (t == 0) {
        float m = lg[0];
        for (int k = 1; k < NCLASS; ++k) m = fmaxf(m, lg[k]);
        float sum = 0.f;
        for (int k = 0; k < NCLASS; ++k) sum += expf(lg[k] - m);
        float ls = logf(sum) + m;
        for (int k = 0; k < NCLASS; ++k) out[gi * NCLASS + k] = lg[k] - ls;
    }
}

extern "C" void kernel_launch(void* const* d_in, const int* in_sizes, int n_in,
                              void* d_out, int out_size, void* d_ws, size_t ws_size,
                              hipStream_t stream) {
    const float* x    = (const float*)d_in[0];
    const int*   ei   = (const int*)d_in[1];
    const int*   src  = ei;
    const int*   dst  = ei + NEDGES;
    const int*   batch= (const int*)d_in[2];
    const float* W1n  = (const float*)d_in[3];
    const float* b1   = (const float*)d_in[4];
    const float* W1s  = (const float*)d_in[5];
    const float* W2n  = (const float*)d_in[6];
    const float* b2   = (const float*)d_in[7];
    const float* W2s  = (const float*)d_in[8];
    const float* W3n  = (const float*)d_in[9];
    const float* b3   = (const float*)d_in[10];
    const float* W3s  = (const float*)d_in[11];
    const float* Wlin = (const float*)d_in[12];
    const float* blin = (const float*)d_in[13];
    float* out = (float*)d_out;

    char* p = (char*)d_ws;
    auto alloc = [&](size_t bytes) -> void* {
        void* r = (void*)p;
        p += (bytes + 255) & ~(size_t)255;
        return r;
    };
    unsigned short* xb   = (unsigned short*)alloc((size_t)NNODES * NFEAT * 2);
    unsigned short* hA   = (unsigned short*)alloc((size_t)NNODES * NHID * 2);
    unsigned short* hB   = (unsigned short*)alloc((size_t)NNODES * NHID * 2);
    unsigned short* wb   = (unsigned short*)alloc((size_t)6 * 16384 * 2);
    int* hist    = (int*)alloc((size_t)NB * HB * 4);
    int* base    = (int*)alloc((size_t)NB * HB * 4);
    int* boff    = (int*)alloc((size_t)(NB + 1) * 4);
    int* row_ptr = (int*)alloc((size_t)(NNODES + 1) * 4);
    int* gstart  = (int*)alloc((size_t)(NGRAPHS + 1) * 4);
    unsigned* ebuf = (unsigned*)alloc((size_t)NEDGES * 4);
    unsigned short* esrc = (unsigned short*)alloc((size_t)NEDGES * 2);
    float* part  = (float*)alloc((size_t)NGRAPHS * 8 * NHID * 4);

    // CSR build (atomic-free counting sort) + graph ranges
    k_hist<<<HB, 256, 0, stream>>>(dst, hist);
    k_scan2<<<1, 512, 0, stream>>>(hist, base, boff, row_ptr, batch, gstart);
    k_scatter<<<HB, 256, 0, stream>>>(src, dst, base, boff, ebuf);
    k_bcsr<<<NB, 256, 0, stream>>>(ebuf, boff, row_ptr, esrc);

    // convert x + weights to bf16 (4 elems/thread)
    {
        int total4 = NNODES * NFEAT / 4 + 6 * 4096;
        k_cvt<<<(total4 + 255) / 256, 256, 0, stream>>>(x, W1n, W1s, W2n, W2s, W3n, W3s, xb, wb);
    }

    const int layerGrid = (NNODES + 63) / 64;

    // fused layers: gather-mean + [agg|feat] @ [Wn|Ws]^T + bias + relu
    k_layer<<<layerGrid, 512, 0, stream>>>(xb, row_ptr, esrc, wb + 0 * 16384, wb + 1 * 16384, b1, hA);
    k_layer<<<layerGrid, 512, 0, stream>>>(hA, row_ptr, esrc, wb + 2 * 16384, wb + 3 * 16384, b2, hB);
    k_layer<<<layerGrid, 512, 0, stream>>>(hB, row_ptr, esrc, wb + 4 * 16384, wb + 5 * 16384, b3, hA);

    // pool + head
    k_pool<<<NGRAPHS * 8, 256, 0, stream>>>(hA, gstart, part);
    k_head<<<NGRAPHS, 128, 0, stream>>>(part, gstart, Wlin, blin, out);
}

// Round 11
// 170.158 us; speedup vs baseline: 1.7643x; 1.3448x over previous
//
#include <hip/hip_runtime.h>
#include <hip/hip_bf16.h>

#define NNODES 50000
#define NEDGES 800000
#define NFEAT 128
#define NHID 128
#define NCLASS 10
#define NGRAPHS 256

#define NB 391   // (NNODES+127)/128 buckets of 128 nodes
#define HB 512   // histogram/scatter blocks

typedef __attribute__((ext_vector_type(8))) short short8;
typedef __attribute__((ext_vector_type(4))) short short4v;
typedef __attribute__((ext_vector_type(4))) float floatx4;

__device__ __forceinline__ float bf2f(unsigned short u) {
    union { unsigned i; float f; } c; c.i = ((unsigned)u) << 16; return c.f;
}
__device__ __forceinline__ unsigned short f2bf(float f) {
    union { float f; unsigned i; } c; c.f = f;
    unsigned x = c.i;
    unsigned r = (x + 0x7fffu + ((x >> 16) & 1u)) >> 16;
    return (unsigned short)r;
}
__device__ __forceinline__ float blo(unsigned v) { return bf2f((unsigned short)(v & 0xffffu)); }
__device__ __forceinline__ float bhi(unsigned v) { return bf2f((unsigned short)(v >> 16)); }

__device__ __forceinline__ void gload_lds16(const void* gsrc, void* ldst) {
    __builtin_amdgcn_global_load_lds(
        (const __attribute__((address_space(1))) void*)gsrc,
        (__attribute__((address_space(3))) void*)ldst, 16, 0, 0);
}

// ---------------- atomic-free CSR build: two-level counting sort ----------------
// hist layout TRANSPOSED: hist[bucket * HB + histblock] so bucket rows are contiguous.
__global__ __launch_bounds__(256) void k_hist(const int* __restrict__ dst,
                                              int* __restrict__ hist) {
    __shared__ int lh[NB];
    int tid = threadIdx.x;
    for (int b = tid; b < NB; b += 256) lh[b] = 0;
    __syncthreads();
    for (int i = blockIdx.x * 256 + tid; i < NEDGES; i += HB * 256)
        atomicAdd(&lh[dst[i] >> 7], 1);
    __syncthreads();
    for (int b = tid; b < NB; b += 256) hist[b * HB + blockIdx.x] = lh[b];
}

// Pass 2a (fully parallel): block q scans its bucket's HB=512 per-block counts.
// Thread t holds elements 2t, 2t+1; wave-scan of pair-sums + LDS cross-wave combine.
__global__ __launch_bounds__(256) void k_scanA(const int* __restrict__ hist,
                                               int* __restrict__ base,
                                               int* __restrict__ tot) {
    int q = blockIdx.x;
    int tid = threadIdx.x;
    int w = tid >> 6, l = tid & 63;
    int v0 = hist[q * HB + 2 * tid];
    int v1 = hist[q * HB + 2 * tid + 1];
    int s = v0 + v1;
    int ps = s;
    #pragma unroll
    for (int d = 1; d < 64; d <<= 1) { int y = __shfl_up(ps, d); if (l >= d) ps += y; }
    __shared__ int wsum[4];
    if (l == 63) wsum[w] = ps;
    __syncthreads();
    int wbase = 0;
    #pragma unroll
    for (int k = 0; k < 4; ++k) wbase += (k < w) ? wsum[k] : 0;
    int excl = wbase + ps - s;                 // exclusive prefix of this thread's pair
    base[q * HB + 2 * tid] = excl;
    base[q * HB + 2 * tid + 1] = excl + v0;
    if (tid == 255) tot[q] = wbase + ps;       // bucket total
}

// Pass 2b (single small block): exclusive scan of NB bucket totals -> boff;
// graph starts via binary search on sorted batch.
__global__ __launch_bounds__(512) void k_scanB(const int* __restrict__ tot,
                                               int* __restrict__ boff,
                                               int* __restrict__ row_ptr,
                                               const int* __restrict__ batch,
                                               int* __restrict__ gstart) {
    int tid = threadIdx.x;
    int wid = tid >> 6, l = tid & 63;
    if (tid <= NGRAPHS) {
        int lo = 0, hi = NNODES;
        while (lo < hi) { int mid = (lo + hi) >> 1; if (batch[mid] < tid) lo = mid + 1; else hi = mid; }
        gstart[tid] = lo;
    }
    if (wid == 0) {
        int carry = 0;
        #pragma unroll
        for (int c = 0; c < (NB + 63) / 64; ++c) {
            int i = c * 64 + l;
            int v = (i < NB) ? tot[i] : 0;
            int s = v;
            #pragma unroll
            for (int d = 1; d < 64; d <<= 1) { int y = __shfl_up(s, d); if (l >= d) s += y; }
            if (i < NB) boff[i] = carry + s - v;
            carry += __shfl(s, 63);
        }
        if (l == 0) { boff[NB] = carry; row_ptr[NNODES] = carry; }
    }
}

// Pass 3: scatter edges into bucket-sorted ebuf; LDS cursors = boff + local base.
__global__ __launch_bounds__(256) void k_scatter(const int* __restrict__ src,
                                                 const int* __restrict__ dst,
                                                 const int* __restrict__ base,
                                                 const int* __restrict__ boff,
                                                 unsigned* __restrict__ ebuf) {
    __shared__ int cur[NB];
    int tid = threadIdx.x;
    for (int b = tid; b < NB; b += 256) cur[b] = boff[b] + base[b * HB + blockIdx.x];
    __syncthreads();
    for (int i = blockIdx.x * 256 + tid; i < NEDGES; i += HB * 256) {
        int d = dst[i];
        int bin = d >> 7;
        int pos = atomicAdd(&cur[bin], 1);                    // LDS atomic
        ebuf[pos] = (unsigned)src[i] | ((unsigned)(d & 127) << 16);
    }
}

// Pass 4: per-bucket local CSR (128 nodes) fully in LDS. esrc stored as ushort.
__global__ __launch_bounds__(256) void k_bcsr(const unsigned* __restrict__ ebuf,
                                              const int* __restrict__ boff,
                                              int* __restrict__ row_ptr,
                                              unsigned short* __restrict__ esrc) {
    __shared__ int deg[128];
    __shared__ int curs[128];
    int tid = threadIdx.x;
    int b = blockIdx.x;
    int s = boff[b], e = boff[b + 1];
    if (tid < 128) deg[tid] = 0;
    __syncthreads();
    for (int i = s + tid; i < e; i += 256) atomicAdd(&deg[ebuf[i] >> 16], 1);
    __syncthreads();
    if (tid == 0) {
        int run = s;
        for (int i = 0; i < 128; ++i) { curs[i] = run; run += deg[i]; }
    }
    __syncthreads();
    if (tid < 128) {
        int node = b * 128 + tid;
        if (node < NNODES) row_ptr[node] = curs[tid];
    }
    __syncthreads();
    for (int i = s + tid; i < e; i += 256) {
        unsigned pk = ebuf[i];
        int pos = atomicAdd(&curs[pk >> 16], 1);              // LDS atomic
        esrc[pos] = (unsigned short)(pk & 0xffffu);
    }
}

// ---------------- bf16 conversion (vectorized x4) of x and all 6 W matrices ------
__global__ void k_cvt(const float* __restrict__ x,
                      const float* __restrict__ w0, const float* __restrict__ w1,
                      const float* __restrict__ w2, const float* __restrict__ w3,
                      const float* __restrict__ w4, const float* __restrict__ w5,
                      unsigned short* __restrict__ xb, unsigned short* __restrict__ wb) {
    int gid = blockIdx.x * blockDim.x + threadIdx.x;   // group of 4 elements
    const int NX4 = NNODES * NFEAT / 4;
    const floatx4* srcv;
    short4v* dstv;
    if (gid < NX4) {
        srcv = (const floatx4*)x + gid;
        dstv = (short4v*)xb + gid;
    } else {
        int j = gid - NX4;
        if (j >= 6 * 4096) return;
        int m = j >> 12;
        int o4 = j & 4095;
        const float* w = (m == 0) ? w0 : (m == 1) ? w1 : (m == 2) ? w2
                       : (m == 3) ? w3 : (m == 4) ? w4 : w5;
        srcv = (const floatx4*)w + o4;
        dstv = (short4v*)wb + (m * 4096 + o4);
    }
    floatx4 v = *srcv;
    short4v o;
    #pragma unroll
    for (int k = 0; k < 4; ++k) o[k] = (short)f2bf(v[k]);
    *dstv = o;
}

// ---------------- fused layer (R8 structure): 64 rows/block, 512 threads ----------
__global__ __launch_bounds__(512, 6) void k_layer(const unsigned short* __restrict__ feat,
                                                  const int* __restrict__ row_ptr,
                                                  const unsigned short* __restrict__ esrc,
                                                  const unsigned short* __restrict__ Bn,
                                                  const unsigned short* __restrict__ Bs,
                                                  const float* __restrict__ bias,
                                                  unsigned short* __restrict__ out) {
    __shared__ __align__(16) unsigned short ldsA[2][8192];   // [0]=agg, [1]=feat: 64 rows x 128
    int w = threadIdx.x >> 6;
    int l = threadIdx.x & 63;
    int r = l & 15;               // row-in-tile for A, col-in-tile for B/C
    int gk = l >> 4;              // k-group (8 elements each)
    int m0 = blockIdx.x * 64;

    // ---- stage A2 = feat rows (x @ Ws operand), pre-swizzled source columns ----
    {
        int c = l & 15;
        #pragma unroll
        for (int is = 0; is < 2; ++is) {
            int row = is * 32 + (w << 2) + (l >> 4);
            int nrow = m0 + row; if (nrow >= NNODES) nrow = NNODES - 1;
            gload_lds16(feat + (size_t)nrow * 128 + ((c ^ (row & 15)) << 3),
                        &ldsA[1][(is * 32 + (w << 2)) * 128]);
        }
    }

    // ---- gather-mean 8 nodes per wave into A1 (swizzled write), 8-deep MLP ----
    const unsigned* feat32 = (const unsigned*)feat;  // 2 bf16/dword, row stride 64
    unsigned* A1 = (unsigned*)&ldsA[0][0];           // dword view, row stride 64
    #pragma unroll 1
    for (int i = 0; i < 8; ++i) {
        int row = (w << 3) + i;
        int n = m0 + row;
        float a0 = 0.f, a1 = 0.f;
        int nb = 0;
        if (n < NNODES) {
            int beg = row_ptr[n];
            nb = row_ptr[n + 1] - beg;
            for (int base = 0; base < nb; base += 64) {
                int rem = nb - base;
                int cnt = rem < 64 ? rem : 64;
                int myidx = (l < cnt) ? (int)esrc[beg + base + l] : 0;
                int j = 0;
                for (; j + 8 <= cnt; j += 8) {
                    int s0 = __shfl(myidx, j);
                    int s1 = __shfl(myidx, j + 1);
                    int s2 = __shfl(myidx, j + 2);
                    int s3 = __shfl(myidx, j + 3);
                    int s4 = __shfl(myidx, j + 4);
                    int s5 = __shfl(myidx, j + 5);
                    int s6 = __shfl(myidx, j + 6);
                    int s7 = __shfl(myidx, j + 7);
                    unsigned v0 = feat32[s0 * 64 + l];
                    unsigned v1 = feat32[s1 * 64 + l];
                    unsigned v2 = feat32[s2 * 64 + l];
                    unsigned v3 = feat32[s3 * 64 + l];
                    unsigned v4 = feat32[s4 * 64 + l];
                    unsigned v5 = feat32[s5 * 64 + l];
                    unsigned v6 = feat32[s6 * 64 + l];
                    unsigned v7 = feat32[s7 * 64 + l];
                    a0 += ((blo(v0) + blo(v1)) + (blo(v2) + blo(v3)))
                        + ((blo(v4) + blo(v5)) + (blo(v6) + blo(v7)));
                    a1 += ((bhi(v0) + bhi(v1)) + (bhi(v2) + bhi(v3)))
                        + ((bhi(v4) + bhi(v5)) + (bhi(v6) + bhi(v7)));
                }
                for (; j + 4 <= cnt; j += 4) {
                    int s0 = __shfl(myidx, j);
                    int s1 = __shfl(myidx, j + 1);
                    int s2 = __shfl(myidx, j + 2);
                    int s3 = __shfl(myidx, j + 3);
                    unsigned v0 = feat32[s0 * 64 + l];
                    unsigned v1 = feat32[s1 * 64 + l];
                    unsigned v2 = feat32[s2 * 64 + l];
                    unsigned v3 = feat32[s3 * 64 + l];
                    a0 += (blo(v0) + blo(v1)) + (blo(v2) + blo(v3));
                    a1 += (bhi(v0) + bhi(v1)) + (bhi(v2) + bhi(v3));
                }
                for (; j < cnt; ++j) {
                    int s0 = __shfl(myidx, j);
                    unsigned v0 = feat32[s0 * 64 + l];
                    a0 += blo(v0);
                    a1 += bhi(v0);
                }
            }
        }
        float inv = 1.0f / (float)max(nb, 1);
        unsigned o = ((unsigned)f2bf(a0 * inv)) | (((unsigned)f2bf(a1 * inv)) << 16);
        int c = l >> 2;                                  // logical 16B chunk 0..15
        A1[row * 64 + ((c ^ (row & 15)) << 2) + (l & 3)] = o;   // swizzled write
    }

    // ---- B fragments (L2-hot, 8 loads) issued before the barrier wait ----
    short8 bf[8];
    #pragma unroll
    for (int kt = 0; kt < 8; ++kt) {
        const unsigned short* Bbase = (kt < 4 ? Bn : Bs);
        bf[kt] = *(const short8*)(Bbase + (w * 16 + r) * 128 + (kt & 3) * 32 + gk * 8);
    }
    int o = w * 16 + r;
    float bias_v = bias[o];

    __syncthreads();   // drains vmcnt (gload_lds) + lgkm (ds_write) for all waves

    // ---- MFMA phase: 4 row-tiles of 16; K processed in 2 halves (VGPR economy) ----
    #pragma unroll
    for (int t = 0; t < 4; ++t) {
        floatx4 acc = {0.f, 0.f, 0.f, 0.f};
        #pragma unroll
        for (int half = 0; half < 2; ++half) {           // 0: agg@Wn, 1: feat@Ws
            short8 af[4];
            #pragma unroll
            for (int kk = 0; kk < 4; ++kk) {
                int Cr = (((kk << 2) + gk) ^ r) << 3;    // swizzled read col
                af[kk] = *(const short8*)(&ldsA[half][(t * 16 + r) * 128 + Cr]);
            }
            #pragma unroll
            for (int kk = 0; kk < 4; ++kk)
                acc = __builtin_amdgcn_mfma_f32_16x16x32_bf16(af[kk], bf[half * 4 + kk], acc, 0, 0, 0);
        }
        // C/D layout: col = lane&15 (=r), row-in-tile = gk*4 + j
        #pragma unroll
        for (int j = 0; j < 4; ++j) {
            int mrow = m0 + t * 16 + gk * 4 + j;
            if (mrow < NNODES) {
                float v = acc[j] + bias_v;
                v = v > 0.f ? v : 0.f;
                out[mrow * 128 + o] = f2bf(v);
            }
        }
    }
}

// ---------------- mean pool: 8 partial-sum blocks per graph ----------------
__global__ __launch_bounds__(256) void k_pool(const unsigned short* __restrict__ h,
                                              const int* __restrict__ gstart,
                                              float* __restrict__ part) {
    int g = blockIdx.x >> 3;
    int c = blockIdx.x & 7;
    int s = gstart[g], e = gstart[g + 1];
    int len = e - s;
    int cs = s + (len * c) / 8;
    int ce = s + (len * (c + 1)) / 8;
    int w = threadIdx.x >> 6;
    int l = threadIdx.x & 63;
    const unsigned* h32 = (const unsigned*)h;
    float a0 = 0.f, a1 = 0.f;
    for (int n = cs + w; n < ce; n += 4) {
        unsigned v = h32[n * 64 + l];
        a0 += blo(v);
        a1 += bhi(v);
    }
    __shared__ float red[4][128];
    red[w][2 * l] = a0;
    red[w][2 * l + 1] = a1;
    __syncthreads();
    if (w == 0) {
        float r0 = (red[0][2 * l] + red[1][2 * l]) + (red[2][2 * l] + red[3][2 * l]);
        float r1 = (red[0][2 * l + 1] + red[1][2 * l + 1]) + (red[2][2 * l + 1] + red[3][2 * l + 1]);
        float* dst = part + (size_t)(g * 8 + c) * 128;
        dst[2 * l] = r0;
        dst[2 * l + 1] = r1;
    }
}

// ---------------- head: reduce partials, logits + log_softmax (f32) ----------------
__global__ __launch_bounds__(128) void k_head(const float* __restrict__ part,
                                              const int* __restrict__ gstart,
                                              const float* __restrict__ Wlin,
                                              const float* __restrict__ blin,
                                              float* __restrict__ out) {
    int gi = blockIdx.x;
    __shared__ float gl[128];
    __shared__ float lg[NCLASS];
    int t = threadIdx.x;
    float s = 0.f;
    #pragma unroll
    for (int c = 0; c < 8; ++c) s += part[(size_t)(gi * 8 + c) * 128 + t];
    int len = gstart[gi + 1] - gstart[gi];
    gl[t] = s / (float)max(len, 1);
    __syncthreads();
    if (t < NCLASS) {
        float a = blin[t];
        #pragma unroll 16
        for (int i = 0; i < 128; ++i) a += gl[i] * Wlin[t * 128 + i];
        lg[t] = a;
    }
    __syncthreads();
    if (t == 0) {
        float m = lg[0];
        for (int k = 1; k < NCLASS; ++k) m = fmaxf(m, lg[k]);
        float sum = 0.f;
        for (int k = 0; k < NCLASS; ++k) sum += expf(lg[k] - m);
        float ls = logf(sum) + m;
        for (int k = 0; k < NCLASS; ++k) out[gi * NCLASS + k] = lg[k] - ls;
    }
}

extern "C" void kernel_launch(void* const* d_in, const int* in_sizes, int n_in,
                              void* d_out, int out_size, void* d_ws, size_t ws_size,
                              hipStream_t stream) {
    const float* x    = (const float*)d_in[0];
    const int*   ei   = (const int*)d_in[1];
    const int*   src  = ei;
    const int*   dst  = ei + NEDGES;
    const int*   batch= (const int*)d_in[2];
    const float* W1n  = (const float*)d_in[3];
    const float* b1   = (const float*)d_in[4];
    const float* W1s  = (const float*)d_in[5];
    const float* W2n  = (const float*)d_in[6];
    const float* b2   = (const float*)d_in[7];
    const float* W2s  = (const float*)d_in[8];
    const float* W3n  = (const float*)d_in[9];
    const float* b3   = (const float*)d_in[10];
    const float* W3s  = (const float*)d_in[11];
    const float* Wlin = (const float*)d_in[12];
    const float* blin = (const float*)d_in[13];
    float* out = (float*)d_out;

    char* p = (char*)d_ws;
    auto alloc = [&](size_t bytes) -> void* {
        void* r = (void*)p;
        p += (bytes + 255) & ~(size_t)255;
        return r;
    };
    unsigned short* xb   = (unsigned short*)alloc((size_t)NNODES * NFEAT * 2);
    unsigned short* hA   = (unsigned short*)alloc((size_t)NNODES * NHID * 2);
    unsigned short* hB   = (unsigned short*)alloc((size_t)NNODES * NHID * 2);
    unsigned short* wb   = (unsigned short*)alloc((size_t)6 * 16384 * 2);
    int* hist    = (int*)alloc((size_t)NB * HB * 4);
    int* base    = (int*)alloc((size_t)NB * HB * 4);
    int* tot     = (int*)alloc((size_t)NB * 4);
    int* boff    = (int*)alloc((size_t)(NB + 1) * 4);
    int* row_ptr = (int*)alloc((size_t)(NNODES + 1) * 4);
    int* gstart  = (int*)alloc((size_t)(NGRAPHS + 1) * 4);
    unsigned* ebuf = (unsigned*)alloc((size_t)NEDGES * 4);
    unsigned short* esrc = (unsigned short*)alloc((size_t)NEDGES * 2);
    float* part  = (float*)alloc((size_t)NGRAPHS * 8 * NHID * 4);

    // CSR build (atomic-free counting sort) + graph ranges
    k_hist<<<HB, 256, 0, stream>>>(dst, hist);
    k_scanA<<<NB, 256, 0, stream>>>(hist, base, tot);
    k_scanB<<<1, 512, 0, stream>>>(tot, boff, row_ptr, batch, gstart);
    k_scatter<<<HB, 256, 0, stream>>>(src, dst, base, boff, ebuf);
    k_bcsr<<<NB, 256, 0, stream>>>(ebuf, boff, row_ptr, esrc);

    // convert x + weights to bf16 (4 elems/thread)
    {
        int total4 = NNODES * NFEAT / 4 + 6 * 4096;
        k_cvt<<<(total4 + 255) / 256, 256, 0, stream>>>(x, W1n, W1s, W2n, W2s, W3n, W3s, xb, wb);
    }

    const int layerGrid = (NNODES + 63) / 64;

    // fused layers: gather-mean + [agg|feat] @ [Wn|Ws]^T + bias + relu
    k_layer<<<layerGrid, 512, 0, stream>>>(xb, row_ptr, esrc, wb + 0 * 16384, wb + 1 * 16384, b1, hA);
    k_layer<<<layerGrid, 512, 0, stream>>>(hA, row_ptr, esrc, wb + 2 * 16384, wb + 3 * 16384, b2, hB);
    k_layer<<<layerGrid, 512, 0, stream>>>(hB, row_ptr, esrc, wb + 4 * 16384, wb + 5 * 16384, b3, hA);

    // pool + head
    k_pool<<<NGRAPHS * 8, 256, 0, stream>>>(hA, gstart, part);
    k_head<<<NGRAPHS, 128, 0, stream>>>(part, gstart, Wlin, blin, out);
}